// Round 16
// baseline (273.592 us; speedup 1.0000x reference)
//
#include <hip/hip_runtime.h>

#define T_LEN 512
#define B_SZ  256
#define N_ST  128

#if defined(__has_builtin)
# if __has_builtin(__builtin_amdgcn_fdot2_f32_bf16)
#  define HAVE_DOT2 1
# endif
#endif
#ifndef HAVE_DOT2
# define HAVE_DOT2 0
#endif

typedef unsigned int uint32;
typedef __bf16 bf16x2 __attribute__((ext_vector_type(2)));
typedef float f2v __attribute__((ext_vector_type(2)));
typedef uint4 __attribute__((may_alias)) uint4a;   // alias-safe LDS vector read

__device__ __forceinline__ uint32 bf16rn(float f) {
    uint32 u = __builtin_bit_cast(uint32, f);
    u += 0x7fffu + ((u >> 16) & 1u);
    return u >> 16;
}
__device__ __forceinline__ uint32 pack2(float lo, float hi) {
    return bf16rn(lo) | (bf16rn(hi) << 16);
}
__device__ __forceinline__ uint32 cvtpk(float lo, float hi) {
    uint32 r;
    asm("v_cvt_pk_bf16_f32 %0, %1, %2" : "=v"(r) : "v"(lo), "v"(hi));
    return r;
}
__device__ __forceinline__ float readlane0(float v) {
    return __builtin_bit_cast(float, (uint32)__builtin_amdgcn_readlane(__builtin_bit_cast(int, v), 0));
}
__device__ __forceinline__ float dot2b(uint32 a, uint32 b, float c) {
#if HAVE_DOT2
    return __builtin_amdgcn_fdot2_f32_bf16(__builtin_bit_cast(bf16x2, a),
                                           __builtin_bit_cast(bf16x2, b), c, false);
#else
    float alo = __builtin_bit_cast(float, a << 16);
    float ahi = __builtin_bit_cast(float, a & 0xffff0000u);
    float blo = __builtin_bit_cast(float, b << 16);
    float bhi = __builtin_bit_cast(float, b & 0xffff0000u);
    return fmaf(ahi, bhi, fmaf(alo, blo, c));
#endif
}

// ws layout (floats): [0..255] logZ_b ; [256..511] score_b ; [512..767] lens (int)

__global__ __launch_bounds__(64) void lengths_kernel(const unsigned char* __restrict__ mask_raw,
                                                     int* __restrict__ lens) {
    int b = blockIdx.x;
    int l = threadIdx.x;
    unsigned char b1 = mask_raw[1], b2 = mask_raw[2];
    int mode = (b1 != 0) ? 0 : ((b2 != 0) ? 2 : 1);
    int cnt = 0;
    if (mode == 0) {
        #pragma unroll
        for (int k = 0; k < 8; ++k) cnt += (mask_raw[(l * 8 + k) * B_SZ + b] != 0);
    } else if (mode == 1) {
        const int* m = (const int*)mask_raw;
        #pragma unroll
        for (int k = 0; k < 8; ++k) cnt += (m[(l * 8 + k) * B_SZ + b] != 0);
    } else {
        const float* m = (const float*)mask_raw;
        #pragma unroll
        for (int k = 0; k < 8; ++k) cnt += (m[(l * 8 + k) * B_SZ + b] != 0.0f);
    }
    #pragma unroll
    for (int off = 1; off < 64; off <<= 1) cnt += __shfl_xor(cnt, off);
    if (l == 0) lens[b] = cnt;
}

// MITM + 2 batches per block: wave0 = forward recurrences of batches {2q, 2q+1}
// interleaved (independent dot2 chains fill each other's stall windows, the
// ~65% of step time R3..R15 could not remove); wave1 = both backward
// recurrences. E packed bf16 (128 VGPR) SHARED by the two batches. Per-batch
// freeze via cond-selects (R4-verified); delayed per-batch normalizer
// (R9-verified). waves_per_eu(1,1): grant the ~180-reg live set (R12-verified
// that the attribute raises the budget; R4's spill at VGPR=84 was pre-attribute).
__global__ void __attribute__((amdgpu_flat_work_group_size(128, 128), amdgpu_waves_per_eu(1, 1)))
forward_kernel(
        const float* __restrict__ emit,
        const float* __restrict__ trans,
        const float* __restrict__ strans,
        const float* __restrict__ etrans,
        const int* __restrict__ lens,
        float* __restrict__ logZ_out) {
    const int q   = blockIdx.x;           // 0..127
    const int bA  = 2 * q, bB = 2 * q + 1;
    const int tid = threadIdx.x;          // 0..127
    const int wid = tid >> 6;             // 0 = fwd both, 1 = bwd both
    const int l   = tid & 63;
    const int c0  = 2 * l, c1 = 2 * l + 1;

    __shared__ alignas(16) uint32 aA32[64], aB32[64];   // fwd states, bf16x2
    __shared__ alignas(16) uint32 zA32[64], zB32[64];   // bwd z vectors, bf16x2
    __shared__ float meetAsh[2][N_ST], meetYsh[2][N_ST];
    __shared__ float maccF[2], maccB[2], red2[2];

    const int lenA = lens[bA], lenB = lens[bB];
    const int mA = (lenA - 1 < 256) ? (lenA - 1) : 256;
    const int mB = (lenB - 1 < 256) ? (lenB - 1) : 256;
    const size_t TS2 = (size_t)B_SZ * N_ST / 2;
    const f2v* evA = (const f2v*)(emit + (size_t)bA * N_ST);
    const f2v* evB = (const f2v*)(emit + (size_t)bB * N_ST);

    if (wid == 0) {
        // ---- forward, both batches; E columns c0,c1 packed over i-pairs ----
        uint32 EA[64], EB[64];
        #pragma unroll
        for (int p = 0; p < 64; ++p) {
            EA[p] = pack2(__expf(trans[(2 * p) * N_ST + c0]), __expf(trans[(2 * p + 1) * N_ST + c0]));
            EB[p] = pack2(__expf(trans[(2 * p) * N_ST + c1]), __expf(trans[(2 * p + 1) * N_ST + c1]));
        }
        const float* ebA = emit + (size_t)bA * N_ST;
        const float* ebB = emit + (size_t)bB * N_ST;
        float aA0 = __expf(strans[c0] + ebA[c0]);
        float aA1 = __expf(strans[c1] + ebA[c1]);
        float aB0 = __expf(strans[c0] + ebB[c0]);
        float aB1 = __expf(strans[c1] + ebB[c1]);
        aA32[l] = pack2(aA0, aA1);
        aB32[l] = pack2(aB0, aB1);
        float MacA = 0.f, MacB = 0.f, invA = 1.0f, invB = 1.0f;
        const int tmax = (mA > mB) ? mA : mB;      // <= 256; emit[t] valid for all t<=tmax+2<512
        f2v ecA = evA[TS2 + l],     ecB = evB[TS2 + l];       // emit[1]
        f2v enA = evA[2 * TS2 + l], enB = evB[2 * TS2 + l];   // emit[2]
        for (int t = 1; t <= tmax; ++t) {
            const f2v e2A = evA[(size_t)(t + 2) * TS2 + l];   // prefetch (t+2 <= 258 < 512)
            const f2v e2B = evB[(size_t)(t + 2) * TS2 + l];
            const float eA0 = __expf(ecA.x), eA1 = __expf(ecA.y);
            const float eB0 = __expf(ecB.x), eB1 = __expf(ecB.y);
            float A0 = 0, A1 = 0, A2 = 0, A3 = 0, B0 = 0, B1 = 0, B2 = 0, B3 = 0;
            float C0 = 0, C1 = 0, C2 = 0, C3 = 0, D0 = 0, D1 = 0, D2 = 0, D3 = 0;
            const uint4a* awA = (const uint4a*)aA32;
            const uint4a* awB = (const uint4a*)aB32;
            #pragma unroll
            for (int p = 0; p < 16; ++p) {
                const uint4 wA = awA[p];               // ds_read_b128 broadcast
                const uint4 wB = awB[p];
                A0 = dot2b(wA.x, EA[4 * p + 0], A0);  B0 = dot2b(wA.x, EB[4 * p + 0], B0);
                C0 = dot2b(wB.x, EA[4 * p + 0], C0);  D0 = dot2b(wB.x, EB[4 * p + 0], D0);
                A1 = dot2b(wA.y, EA[4 * p + 1], A1);  B1 = dot2b(wA.y, EB[4 * p + 1], B1);
                C1 = dot2b(wB.y, EA[4 * p + 1], C1);  D1 = dot2b(wB.y, EB[4 * p + 1], D1);
                A2 = dot2b(wA.z, EA[4 * p + 2], A2);  B2 = dot2b(wA.z, EB[4 * p + 2], B2);
                C2 = dot2b(wB.z, EA[4 * p + 2], C2);  D2 = dot2b(wB.z, EB[4 * p + 2], D2);
                A3 = dot2b(wA.w, EA[4 * p + 3], A3);  B3 = dot2b(wA.w, EB[4 * p + 3], B3);
                C3 = dot2b(wB.w, EA[4 * p + 3], C3);  D3 = dot2b(wB.w, EB[4 * p + 3], D3);
            }
            const float rA0 = (A0 + A1) + (A2 + A3);
            const float rA1 = (B0 + B1) + (B2 + B3);
            const float rB0 = (C0 + C1) + (C2 + C3);
            const float rB1 = (D0 + D1) + (D2 + D3);
            const bool cA = (t <= mA), cB = (t <= mB);
            MacA -= cA ? __logf(invA) : 0.0f;          // bookkeeping, gated
            MacB -= cB ? __logf(invB) : 0.0f;
            aA0 = cA ? eA0 * rA0 * invA : aA0;         // delayed normalizer, frozen past mX
            aA1 = cA ? eA1 * rA1 * invA : aA1;
            aB0 = cB ? eB0 * rB0 * invB : aB0;
            aB1 = cB ? eB1 * rB1 * invB : aB1;
            aA32[l] = cvtpk(aA0, aA1);                 // one ds_write_b32 each
            aB32[l] = cvtpk(aB0, aB1);
            invA = __builtin_amdgcn_rcpf(readlane0(rA0));  // junk past mA: never applied
            invB = __builtin_amdgcn_rcpf(readlane0(rB0));
            ecA = enA; enA = e2A; ecB = enB; enB = e2B;
        }
        meetAsh[0][c0] = aA0; meetAsh[0][c1] = aA1;
        meetAsh[1][c0] = aB0; meetAsh[1][c1] = aB1;
        if (l == 0) { maccF[0] = MacA; maccF[1] = MacB; }
    } else {
        // ---- backward, both batches; E rows c0,c1 packed over j-pairs ----
        uint32 RA[64], RB[64];
        #pragma unroll
        for (int p = 0; p < 64; ++p) {
            RA[p] = pack2(__expf(trans[c0 * N_ST + 2 * p]), __expf(trans[c0 * N_ST + 2 * p + 1]));
            RB[p] = pack2(__expf(trans[c1 * N_ST + 2 * p]), __expf(trans[c1 * N_ST + 2 * p + 1]));
        }
        float yA0 = __expf(etrans[c0]), yA1 = __expf(etrans[c1]);   // y_{len-1}
        float yB0 = yA0,                yB1 = yA1;
        float MacA = 0.f, MacB = 0.f, invA = 1.0f, invB = 1.0f;
        const int smax = ((lenA > lenB) ? lenA : lenB) - 1;
        const int smin = ((mA < mB) ? mA : mB) + 1;    // >= 256, so all emit[s] valid
        f2v ecA = evA[(size_t)smax * TS2 + l],       ecB = evB[(size_t)smax * TS2 + l];
        f2v enA = evA[(size_t)(smax - 1) * TS2 + l], enB = evB[(size_t)(smax - 1) * TS2 + l];
        for (int s = smax; s >= smin; --s) {
            const int sp = (s - 2 >= smin) ? s - 2 : smin;
            const f2v e2A = evA[(size_t)sp * TS2 + l];
            const f2v e2B = evB[(size_t)sp * TS2 + l];
            const float eA0 = __expf(ecA.x), eA1 = __expf(ecA.y);
            const float eB0 = __expf(ecB.x), eB1 = __expf(ecB.y);
            zA32[l] = cvtpk(eA0 * yA0, eA1 * yA1);     // z = ee_s o y_s (junk if idle: gated below)
            zB32[l] = cvtpk(eB0 * yB0, eB1 * yB1);
            float A0 = 0, A1 = 0, A2 = 0, A3 = 0, B0 = 0, B1 = 0, B2 = 0, B3 = 0;
            float C0 = 0, C1 = 0, C2 = 0, C3 = 0, D0 = 0, D1 = 0, D2 = 0, D3 = 0;
            const uint4a* zwA = (const uint4a*)zA32;
            const uint4a* zwB = (const uint4a*)zB32;
            #pragma unroll
            for (int p = 0; p < 16; ++p) {
                const uint4 wA = zwA[p];
                const uint4 wB = zwB[p];
                A0 = dot2b(wA.x, RA[4 * p + 0], A0);  B0 = dot2b(wA.x, RB[4 * p + 0], B0);
                C0 = dot2b(wB.x, RA[4 * p + 0], C0);  D0 = dot2b(wB.x, RB[4 * p + 0], D0);
                A1 = dot2b(wA.y, RA[4 * p + 1], A1);  B1 = dot2b(wA.y, RB[4 * p + 1], B1);
                C1 = dot2b(wB.y, RA[4 * p + 1], C1);  D1 = dot2b(wB.y, RB[4 * p + 1], D1);
                A2 = dot2b(wA.z, RA[4 * p + 2], A2);  B2 = dot2b(wA.z, RB[4 * p + 2], B2);
                C2 = dot2b(wB.z, RA[4 * p + 2], C2);  D2 = dot2b(wB.z, RB[4 * p + 2], D2);
                A3 = dot2b(wA.w, RA[4 * p + 3], A3);  B3 = dot2b(wA.w, RB[4 * p + 3], B3);
                C3 = dot2b(wB.w, RA[4 * p + 3], C3);  D3 = dot2b(wB.w, RB[4 * p + 3], D3);
            }
            const float rA0 = (A0 + A1) + (A2 + A3);
            const float rA1 = (B0 + B1) + (B2 + B3);
            const float rB0 = (C0 + C1) + (C2 + C3);
            const float rB1 = (D0 + D1) + (D2 + D3);
            // batch active window: mX+1 <= s <= lenX-1
            const bool cA = (s <= lenA - 1) && (s >= mA + 1);
            const bool cB = (s <= lenB - 1) && (s >= mB + 1);
            MacA -= cA ? __logf(invA) : 0.0f;
            MacB -= cB ? __logf(invB) : 0.0f;
            yA0 = cA ? rA0 * invA : yA0;
            yA1 = cA ? rA1 * invA : yA1;
            yB0 = cB ? rB0 * invB : yB0;
            yB1 = cB ? rB1 * invB : yB1;
            invA = cA ? __builtin_amdgcn_rcpf(readlane0(rA0)) : invA;  // keep 1.0 until active
            invB = cB ? __builtin_amdgcn_rcpf(readlane0(rB0)) : invB;
            ecA = enA; enA = e2A; ecB = enB; enB = e2B;
        }
        meetYsh[0][c0] = yA0; meetYsh[0][c1] = yA1;
        meetYsh[1][c0] = yB0; meetYsh[1][c1] = yB1;
        if (l == 0) { maccB[0] = MacA; maccB[1] = MacB; }
    }

    // ---- meet: wave wid reduces batch wid ----
    __syncthreads();
    float v = meetAsh[wid][l] * meetYsh[wid][l] + meetAsh[wid][l + 64] * meetYsh[wid][l + 64];
    #pragma unroll
    for (int off = 1; off < 64; off <<= 1) v += __shfl_xor(v, off);
    if (l == 0) logZ_out[2 * q + wid] = maccF[wid] + maccB[wid] + __logf(v);
    (void)red2;
}

__global__ __launch_bounds__(128) void score_kernel(
        const float* __restrict__ emit,
        const int* __restrict__ target,
        const float* __restrict__ trans,
        const float* __restrict__ strans,
        const float* __restrict__ etrans,
        const int* __restrict__ lens,
        float* __restrict__ score_out) {
    const int b   = blockIdx.x;
    const int tid = threadIdx.x;
    const int len = lens[b];
    float local = 0.f;
    for (int t = tid; t < len; t += 128) {
        int tgt = target[t * B_SZ + b];
        float v = emit[(size_t)t * (B_SZ * N_ST) + b * N_ST + tgt];
        if (t > 0) v += trans[target[(t - 1) * B_SZ + b] * N_ST + tgt];
        local += v;
    }
    if (tid == 0) {
        local += strans[target[b]];
        local += etrans[target[(len - 1) * B_SZ + b]];
    }
    #pragma unroll
    for (int off = 1; off < 64; off <<= 1) local += __shfl_xor(local, off);
    __shared__ float partial[2];
    if ((tid & 63) == 0) partial[tid >> 6] = local;
    __syncthreads();
    if (tid == 0) score_out[b] = partial[0] + partial[1];
}

__global__ __launch_bounds__(256) void finalize_kernel(
        const float* __restrict__ logZ,
        const float* __restrict__ score,
        float* __restrict__ out) {
    int tid = threadIdx.x;
    float v = logZ[tid] - score[tid];
    #pragma unroll
    for (int off = 1; off < 64; off <<= 1) v += __shfl_xor(v, off);
    __shared__ float p[4];
    if ((tid & 63) == 0) p[tid >> 6] = v;
    __syncthreads();
    if (tid == 0) out[0] = (p[0] + p[1] + p[2] + p[3]) / 256.0f;
}

extern "C" void kernel_launch(void* const* d_in, const int* in_sizes, int n_in,
                              void* d_out, int out_size, void* d_ws, size_t ws_size,
                              hipStream_t stream) {
    const float*         emit   = (const float*)d_in[0];
    const int*           target = (const int*)d_in[1];
    const unsigned char* mask   = (const unsigned char*)d_in[2];
    const float*         trans  = (const float*)d_in[3];
    const float*         strans = (const float*)d_in[4];
    const float*         etrans = (const float*)d_in[5];

    float* ws     = (float*)d_ws;
    float* logZb  = ws;            // 256
    float* scoreb = ws + 256;      // 256
    int*   lens   = (int*)(ws + 512);

    lengths_kernel<<<B_SZ, 64, 0, stream>>>(mask, lens);
    forward_kernel<<<B_SZ / 2, 128, 0, stream>>>(emit, trans, strans, etrans, lens, logZb);
    score_kernel<<<B_SZ, 128, 0, stream>>>(emit, target, trans, strans, etrans, lens, scoreb);
    finalize_kernel<<<1, 256, 0, stream>>>(logZb, scoreb, (float*)d_out);
}

// Round 17
// 128.170 us; speedup vs baseline: 2.1346x; 2.1346x over previous
//
#include <hip/hip_runtime.h>

#define T_LEN 512
#define B_SZ  256
#define N_ST  128

#if defined(__has_builtin)
# if __has_builtin(__builtin_amdgcn_fdot2_f32_bf16)
#  define HAVE_DOT2 1
# endif
#endif
#ifndef HAVE_DOT2
# define HAVE_DOT2 0
#endif

typedef unsigned int uint32;
typedef __bf16 bf16x2 __attribute__((ext_vector_type(2)));
typedef float f2v __attribute__((ext_vector_type(2)));
typedef uint4 __attribute__((may_alias)) uint4a;   // alias-safe LDS vector read

__device__ __forceinline__ uint32 bf16rn(float f) {
    uint32 u = __builtin_bit_cast(uint32, f);
    u += 0x7fffu + ((u >> 16) & 1u);
    return u >> 16;
}
__device__ __forceinline__ uint32 pack2(float lo, float hi) {
    return bf16rn(lo) | (bf16rn(hi) << 16);
}
__device__ __forceinline__ uint32 cvtpk(float lo, float hi) {
    uint32 r;
    asm("v_cvt_pk_bf16_f32 %0, %1, %2" : "=v"(r) : "v"(lo), "v"(hi));
    return r;
}
__device__ __forceinline__ float readlane0(float v) {
    return __builtin_bit_cast(float, (uint32)__builtin_amdgcn_readlane(__builtin_bit_cast(int, v), 0));
}
__device__ __forceinline__ float dot2b(uint32 a, uint32 b, float c) {
#if HAVE_DOT2
    return __builtin_amdgcn_fdot2_f32_bf16(__builtin_bit_cast(bf16x2, a),
                                           __builtin_bit_cast(bf16x2, b), c, false);
#else
    float alo = __builtin_bit_cast(float, a << 16);
    float ahi = __builtin_bit_cast(float, a & 0xffff0000u);
    float blo = __builtin_bit_cast(float, b << 16);
    float bhi = __builtin_bit_cast(float, b & 0xffff0000u);
    return fmaf(ahi, bhi, fmaf(alo, blo, c));
#endif
}

// ws (floats): [0..255] logZ | [256..511] score | [512..767] lens(int) |
// [768..1023] MaccF | [1024..1279] MaccB | [1280..34047] U(256x128) | [34048..66815] Y(256x128)
#define WS_NEED_BYTES (66816 * 4)

__global__ __launch_bounds__(64) void lengths_kernel(const unsigned char* __restrict__ mask_raw,
                                                     int* __restrict__ lens) {
    int b = blockIdx.x;
    int l = threadIdx.x;
    unsigned char b1 = mask_raw[1], b2 = mask_raw[2];
    int mode = (b1 != 0) ? 0 : ((b2 != 0) ? 2 : 1);
    int cnt = 0;
    if (mode == 0) {
        #pragma unroll
        for (int k = 0; k < 8; ++k) cnt += (mask_raw[(l * 8 + k) * B_SZ + b] != 0);
    } else if (mode == 1) {
        const int* m = (const int*)mask_raw;
        #pragma unroll
        for (int k = 0; k < 8; ++k) cnt += (m[(l * 8 + k) * B_SZ + b] != 0);
    } else {
        const float* m = (const float*)mask_raw;
        #pragma unroll
        for (int k = 0; k < 8; ++k) cnt += (m[(l * 8 + k) * B_SZ + b] != 0.0f);
    }
    #pragma unroll
    for (int off = 1; off < 64; off <<= 1) cnt += __shfl_xor(cnt, off);
    if (l == 0) lens[b] = cnt;
}

// Split-direction MITM: block 2b = forward recurrence of batch b, block 2b+1 =
// backward recurrence. ONE wave per block -> each recurrence gets its own SIMD
// (R14's 18% VALUBusy is consistent with both waves of a block issue-serializing
// on one SIMD; this is the direct test). Bodies identical to R14's branches.
__global__ void __attribute__((amdgpu_flat_work_group_size(64, 64), amdgpu_waves_per_eu(1, 1)))
forward_split(
        const float* __restrict__ emit,
        const float* __restrict__ trans,
        const float* __restrict__ strans,
        const float* __restrict__ etrans,
        const int* __restrict__ lens,
        float* __restrict__ wsMF, float* __restrict__ wsMB,
        float* __restrict__ wsU, float* __restrict__ wsY) {
    const int b   = blockIdx.x >> 1;
    const int dir = blockIdx.x & 1;       // 0 = forward, 1 = backward
    const int l   = threadIdx.x;          // 0..63
    const int c0  = 2 * l, c1 = 2 * l + 1;

    __shared__ alignas(16) uint32 s32[64];   // state vector, bf16x2 packed

    const int len = lens[b];
    const int m = (len - 1 < 256) ? (len - 1) : 256;
    const float* eb = emit + (size_t)b * N_ST;
    const size_t TS2 = (size_t)B_SZ * N_ST / 2;
    const f2v* ebv = (const f2v*)eb;

    if (dir == 0) {
        // ---- forward: E columns c0, c1 packed over i-pairs ----
        uint32 EA[64], EB[64];
        #pragma unroll
        for (int p = 0; p < 64; ++p) {
            EA[p] = pack2(__expf(trans[(2 * p) * N_ST + c0]), __expf(trans[(2 * p + 1) * N_ST + c0]));
            EB[p] = pack2(__expf(trans[(2 * p) * N_ST + c1]), __expf(trans[(2 * p + 1) * N_ST + c1]));
        }
        float aA = __expf(strans[c0] + eb[c0]);
        float aB = __expf(strans[c1] + eb[c1]);
        s32[l] = pack2(aA, aB);
        float Macc = 0.f, inv = 1.0f;
        #define EIDX(T) ((size_t)(((T) <= m) ? (T) : m) * TS2 + l)
        f2v p0 = ebv[EIDX(1)];
        f2v p1 = ebv[EIDX(2)];
        f2v p2 = ebv[EIDX(3)];
        f2v p3 = ebv[EIDX(4)];
        for (int t = 1; t <= m; ++t) {
            const f2v pn = ebv[EIDX(t + 4)];
            const float ee0 = __expf(p0.x), ee1 = __expf(p0.y);
            float A0 = 0, A1 = 0, A2 = 0, A3 = 0, B0 = 0, B1 = 0, B2 = 0, B3 = 0;
            const uint4a* aw = (const uint4a*)s32;
            #pragma unroll
            for (int q = 0; q < 16; ++q) {
                const uint4 w = aw[q];                 // ds_read_b128 broadcast
                A0 = dot2b(w.x, EA[4 * q + 0], A0);  B0 = dot2b(w.x, EB[4 * q + 0], B0);
                A1 = dot2b(w.y, EA[4 * q + 1], A1);  B1 = dot2b(w.y, EB[4 * q + 1], B1);
                A2 = dot2b(w.z, EA[4 * q + 2], A2);  B2 = dot2b(w.z, EB[4 * q + 2], B2);
                A3 = dot2b(w.w, EA[4 * q + 3], A3);  B3 = dot2b(w.w, EB[4 * q + 3], B3);
            }
            const float rA = (A0 + A1) + (A2 + A3);
            const float rB = (B0 + B1) + (B2 + B3);
            Macc -= __logf(inv);
            aA = ee0 * rA * inv;
            aB = ee1 * rB * inv;
            s32[l] = cvtpk(aA, aB);                    // one ds_write_b32
            inv = __builtin_amdgcn_rcpf(readlane0(rA));
            p0 = p1; p1 = p2; p2 = p3; p3 = pn;
        }
        #undef EIDX
        wsU[b * N_ST + c0] = aA;
        wsU[b * N_ST + c1] = aB;
        if (l == 0) wsMF[b] = Macc;
    } else {
        // ---- backward: E rows c0, c1 packed over j-pairs ----
        uint32 RA[64], RB[64];
        #pragma unroll
        for (int p = 0; p < 64; ++p) {
            RA[p] = pack2(__expf(trans[c0 * N_ST + 2 * p]), __expf(trans[c0 * N_ST + 2 * p + 1]));
            RB[p] = pack2(__expf(trans[c1 * N_ST + 2 * p]), __expf(trans[c1 * N_ST + 2 * p + 1]));
        }
        float y0 = __expf(etrans[c0]);
        float y1 = __expf(etrans[c1]);
        float Maccb = 0.f, invb = 1.0f;
        const int t0 = len - 1;
        #define EIDXB(T) ((size_t)(((T) > m) ? (T) : (m + 1)) * TS2 + l)
        f2v p0 = ebv[EIDXB(t0)];
        f2v p1 = ebv[EIDXB(t0 - 1)];
        f2v p2 = ebv[EIDXB(t0 - 2)];
        f2v p3 = ebv[EIDXB(t0 - 3)];
        for (int t = t0; t > m; --t) {
            const f2v pn = ebv[EIDXB(t - 4)];
            const float ee0 = __expf(p0.x), ee1 = __expf(p0.y);
            s32[l] = cvtpk(ee0 * y0, ee1 * y1);        // z = ee_t o y_t
            float R0 = 0, R1 = 0, R2 = 0, R3 = 0, S0 = 0, S1 = 0, S2 = 0, S3 = 0;
            const uint4a* zw = (const uint4a*)s32;
            #pragma unroll
            for (int q = 0; q < 16; ++q) {
                const uint4 w = zw[q];
                R0 = dot2b(w.x, RA[4 * q + 0], R0);  S0 = dot2b(w.x, RB[4 * q + 0], S0);
                R1 = dot2b(w.y, RA[4 * q + 1], R1);  S1 = dot2b(w.y, RB[4 * q + 1], S1);
                R2 = dot2b(w.z, RA[4 * q + 2], R2);  S2 = dot2b(w.z, RB[4 * q + 2], S2);
                R3 = dot2b(w.w, RA[4 * q + 3], R3);  S3 = dot2b(w.w, RB[4 * q + 3], S3);
            }
            const float rR = (R0 + R1) + (R2 + R3);
            const float rS = (S0 + S1) + (S2 + S3);
            Maccb -= __logf(invb);
            y0 = rR * invb;
            y1 = rS * invb;
            invb = __builtin_amdgcn_rcpf(readlane0(rR));
            p0 = p1; p1 = p2; p2 = p3; p3 = pn;
        }
        #undef EIDXB
        wsY[b * N_ST + c0] = y0;
        wsY[b * N_ST + c1] = y1;
        if (l == 0) wsMB[b] = Maccb;
    }
}

__global__ __launch_bounds__(64) void combine_kernel(
        const float* __restrict__ wsU, const float* __restrict__ wsY,
        const float* __restrict__ wsMF, const float* __restrict__ wsMB,
        float* __restrict__ logZ) {
    const int b = blockIdx.x;
    const int l = threadIdx.x;
    float v = wsU[b * N_ST + l] * wsY[b * N_ST + l]
            + wsU[b * N_ST + l + 64] * wsY[b * N_ST + l + 64];
    #pragma unroll
    for (int off = 1; off < 64; off <<= 1) v += __shfl_xor(v, off);
    if (l == 0) logZ[b] = wsMF[b] + wsMB[b] + __logf(v);
}

// ---------------- R14 fused fallback (proven, 123 us): used if ws too small ----------------
__global__ void __attribute__((amdgpu_flat_work_group_size(128, 128), amdgpu_waves_per_eu(1, 1)))
forward_fused(
        const float* __restrict__ emit,
        const float* __restrict__ trans,
        const float* __restrict__ strans,
        const float* __restrict__ etrans,
        const int* __restrict__ lens,
        float* __restrict__ logZ_out) {
    const int b   = blockIdx.x;
    const int tid = threadIdx.x;
    const int wid = tid >> 6;
    const int l   = tid & 63;
    const int c0  = 2 * l, c1 = 2 * l + 1;

    __shared__ alignas(16) uint32 a32[64];
    __shared__ alignas(16) uint32 z32[64];
    __shared__ float meetA[N_ST], meetY[N_ST];
    __shared__ float maccSh[2], red2[2];

    const int len = lens[b];
    const int m = (len - 1 < 256) ? (len - 1) : 256;
    const float* eb = emit + (size_t)b * N_ST;
    const size_t TS2 = (size_t)B_SZ * N_ST / 2;
    const f2v* ebv = (const f2v*)eb;

    if (wid == 0) {
        uint32 EA[64], EB[64];
        #pragma unroll
        for (int p = 0; p < 64; ++p) {
            EA[p] = pack2(__expf(trans[(2 * p) * N_ST + c0]), __expf(trans[(2 * p + 1) * N_ST + c0]));
            EB[p] = pack2(__expf(trans[(2 * p) * N_ST + c1]), __expf(trans[(2 * p + 1) * N_ST + c1]));
        }
        float aA = __expf(strans[c0] + eb[c0]);
        float aB = __expf(strans[c1] + eb[c1]);
        a32[l] = pack2(aA, aB);
        float Macc = 0.f, inv = 1.0f;
        #define EIDX(T) ((size_t)(((T) <= m) ? (T) : m) * TS2 + l)
        f2v p0 = ebv[EIDX(1)];
        f2v p1 = ebv[EIDX(2)];
        f2v p2 = ebv[EIDX(3)];
        f2v p3 = ebv[EIDX(4)];
        for (int t = 1; t <= m; ++t) {
            const f2v pn = ebv[EIDX(t + 4)];
            const float ee0 = __expf(p0.x), ee1 = __expf(p0.y);
            float A0 = 0, A1 = 0, A2 = 0, A3 = 0, B0 = 0, B1 = 0, B2 = 0, B3 = 0;
            const uint4a* aw = (const uint4a*)a32;
            #pragma unroll
            for (int q = 0; q < 16; ++q) {
                const uint4 w = aw[q];
                A0 = dot2b(w.x, EA[4 * q + 0], A0);  B0 = dot2b(w.x, EB[4 * q + 0], B0);
                A1 = dot2b(w.y, EA[4 * q + 1], A1);  B1 = dot2b(w.y, EB[4 * q + 1], B1);
                A2 = dot2b(w.z, EA[4 * q + 2], A2);  B2 = dot2b(w.z, EB[4 * q + 2], B2);
                A3 = dot2b(w.w, EA[4 * q + 3], A3);  B3 = dot2b(w.w, EB[4 * q + 3], B3);
            }
            const float rA = (A0 + A1) + (A2 + A3);
            const float rB = (B0 + B1) + (B2 + B3);
            Macc -= __logf(inv);
            aA = ee0 * rA * inv;
            aB = ee1 * rB * inv;
            a32[l] = cvtpk(aA, aB);
            inv = __builtin_amdgcn_rcpf(readlane0(rA));
            p0 = p1; p1 = p2; p2 = p3; p3 = pn;
        }
        #undef EIDX
        meetA[c0] = aA; meetA[c1] = aB;
        if (l == 0) maccSh[0] = Macc;
    } else {
        uint32 RA[64], RB[64];
        #pragma unroll
        for (int p = 0; p < 64; ++p) {
            RA[p] = pack2(__expf(trans[c0 * N_ST + 2 * p]), __expf(trans[c0 * N_ST + 2 * p + 1]));
            RB[p] = pack2(__expf(trans[c1 * N_ST + 2 * p]), __expf(trans[c1 * N_ST + 2 * p + 1]));
        }
        float y0 = __expf(etrans[c0]);
        float y1 = __expf(etrans[c1]);
        float Maccb = 0.f, invb = 1.0f;
        const int t0 = len - 1;
        #define EIDXB(T) ((size_t)(((T) > m) ? (T) : (m + 1)) * TS2 + l)
        f2v p0 = ebv[EIDXB(t0)];
        f2v p1 = ebv[EIDXB(t0 - 1)];
        f2v p2 = ebv[EIDXB(t0 - 2)];
        f2v p3 = ebv[EIDXB(t0 - 3)];
        for (int t = t0; t > m; --t) {
            const f2v pn = ebv[EIDXB(t - 4)];
            const float ee0 = __expf(p0.x), ee1 = __expf(p0.y);
            z32[l] = cvtpk(ee0 * y0, ee1 * y1);
            float R0 = 0, R1 = 0, R2 = 0, R3 = 0, S0 = 0, S1 = 0, S2 = 0, S3 = 0;
            const uint4a* zw = (const uint4a*)z32;
            #pragma unroll
            for (int q = 0; q < 16; ++q) {
                const uint4 w = zw[q];
                R0 = dot2b(w.x, RA[4 * q + 0], R0);  S0 = dot2b(w.x, RB[4 * q + 0], S0);
                R1 = dot2b(w.y, RA[4 * q + 1], R1);  S1 = dot2b(w.y, RB[4 * q + 1], S1);
                R2 = dot2b(w.z, RA[4 * q + 2], R2);  S2 = dot2b(w.z, RB[4 * q + 2], S2);
                R3 = dot2b(w.w, RA[4 * q + 3], R3);  S3 = dot2b(w.w, RB[4 * q + 3], S3);
            }
            const float rR = (R0 + R1) + (R2 + R3);
            const float rS = (S0 + S1) + (S2 + S3);
            Maccb -= __logf(invb);
            y0 = rR * invb;
            y1 = rS * invb;
            invb = __builtin_amdgcn_rcpf(readlane0(rR));
            p0 = p1; p1 = p2; p2 = p3; p3 = pn;
        }
        #undef EIDXB
        meetY[c0] = y0; meetY[c1] = y1;
        if (l == 0) maccSh[1] = Maccb;
    }

    __syncthreads();
    float v = meetA[tid] * meetY[tid];
    #pragma unroll
    for (int off = 1; off < 64; off <<= 1) v += __shfl_xor(v, off);
    if (l == 0) red2[wid] = v;
    __syncthreads();
    if (tid == 0) logZ_out[b] = maccSh[0] + maccSh[1] + __logf(red2[0] + red2[1]);
}

__global__ __launch_bounds__(128) void score_kernel(
        const float* __restrict__ emit,
        const int* __restrict__ target,
        const float* __restrict__ trans,
        const float* __restrict__ strans,
        const float* __restrict__ etrans,
        const int* __restrict__ lens,
        float* __restrict__ score_out) {
    const int b   = blockIdx.x;
    const int tid = threadIdx.x;
    const int len = lens[b];
    float local = 0.f;
    for (int t = tid; t < len; t += 128) {
        int tgt = target[t * B_SZ + b];
        float v = emit[(size_t)t * (B_SZ * N_ST) + b * N_ST + tgt];
        if (t > 0) v += trans[target[(t - 1) * B_SZ + b] * N_ST + tgt];
        local += v;
    }
    if (tid == 0) {
        local += strans[target[b]];
        local += etrans[target[(len - 1) * B_SZ + b]];
    }
    #pragma unroll
    for (int off = 1; off < 64; off <<= 1) local += __shfl_xor(local, off);
    __shared__ float partial[2];
    if ((tid & 63) == 0) partial[tid >> 6] = local;
    __syncthreads();
    if (tid == 0) score_out[b] = partial[0] + partial[1];
}

__global__ __launch_bounds__(256) void finalize_kernel(
        const float* __restrict__ logZ,
        const float* __restrict__ score,
        float* __restrict__ out) {
    int tid = threadIdx.x;
    float v = logZ[tid] - score[tid];
    #pragma unroll
    for (int off = 1; off < 64; off <<= 1) v += __shfl_xor(v, off);
    __shared__ float p[4];
    if ((tid & 63) == 0) p[tid >> 6] = v;
    __syncthreads();
    if (tid == 0) out[0] = (p[0] + p[1] + p[2] + p[3]) / 256.0f;
}

extern "C" void kernel_launch(void* const* d_in, const int* in_sizes, int n_in,
                              void* d_out, int out_size, void* d_ws, size_t ws_size,
                              hipStream_t stream) {
    const float*         emit   = (const float*)d_in[0];
    const int*           target = (const int*)d_in[1];
    const unsigned char* mask   = (const unsigned char*)d_in[2];
    const float*         trans  = (const float*)d_in[3];
    const float*         strans = (const float*)d_in[4];
    const float*         etrans = (const float*)d_in[5];

    float* ws     = (float*)d_ws;
    float* logZb  = ws;                 // 256
    float* scoreb = ws + 256;           // 256
    int*   lens   = (int*)(ws + 512);   // 256
    float* wsMF   = ws + 768;           // 256
    float* wsMB   = ws + 1024;          // 256
    float* wsU    = ws + 1280;          // 256*128
    float* wsY    = ws + 34048;         // 256*128

    lengths_kernel<<<B_SZ, 64, 0, stream>>>(mask, lens);
    if (ws_size >= (size_t)WS_NEED_BYTES) {
        forward_split<<<2 * B_SZ, 64, 0, stream>>>(emit, trans, strans, etrans, lens,
                                                   wsMF, wsMB, wsU, wsY);
        combine_kernel<<<B_SZ, 64, 0, stream>>>(wsU, wsY, wsMF, wsMB, logZb);
    } else {
        forward_fused<<<B_SZ, 128, 0, stream>>>(emit, trans, strans, etrans, lens, logZb);
    }
    score_kernel<<<B_SZ, 128, 0, stream>>>(emit, target, trans, strans, etrans, lens, scoreb);
    finalize_kernel<<<1, 256, 0, stream>>>(logZb, scoreb, (float*)d_out);
}

// Round 18
// 117.560 us; speedup vs baseline: 2.3273x; 1.0903x over previous
//
#include <hip/hip_runtime.h>

#define T_LEN 512
#define B_SZ  256
#define N_ST  128

#if defined(__has_builtin)
# if __has_builtin(__builtin_amdgcn_fdot2_f32_bf16)
#  define HAVE_DOT2 1
# endif
#endif
#ifndef HAVE_DOT2
# define HAVE_DOT2 0
#endif

typedef unsigned int uint32;
typedef __bf16 bf16x2 __attribute__((ext_vector_type(2)));
typedef float f2v __attribute__((ext_vector_type(2)));
typedef uint4 __attribute__((may_alias)) uint4a;   // alias-safe LDS vector read

__device__ __forceinline__ uint32 bf16rn(float f) {
    uint32 u = __builtin_bit_cast(uint32, f);
    u += 0x7fffu + ((u >> 16) & 1u);
    return u >> 16;
}
__device__ __forceinline__ uint32 pack2(float lo, float hi) {
    return bf16rn(lo) | (bf16rn(hi) << 16);
}
__device__ __forceinline__ uint32 cvtpk(float lo, float hi) {
    uint32 r;
    asm("v_cvt_pk_bf16_f32 %0, %1, %2" : "=v"(r) : "v"(lo), "v"(hi));
    return r;
}
__device__ __forceinline__ float readlane0(float v) {
    return __builtin_bit_cast(float, (uint32)__builtin_amdgcn_readlane(__builtin_bit_cast(int, v), 0));
}
__device__ __forceinline__ float dot2b(uint32 a, uint32 b, float c) {
#if HAVE_DOT2
    return __builtin_amdgcn_fdot2_f32_bf16(__builtin_bit_cast(bf16x2, a),
                                           __builtin_bit_cast(bf16x2, b), c, false);
#else
    float alo = __builtin_bit_cast(float, a << 16);
    float ahi = __builtin_bit_cast(float, a & 0xffff0000u);
    float blo = __builtin_bit_cast(float, b << 16);
    float bhi = __builtin_bit_cast(float, b & 0xffff0000u);
    return fmaf(ahi, bhi, fmaf(alo, blo, c));
#endif
}

// Per-wave length computation: 64 lanes x 8 mask entries for batch b.
// Each wave derives len independently -- no cross-wave sync needed.
__device__ __forceinline__ int wave_len(const unsigned char* __restrict__ mask_raw, int b, int l) {
    unsigned char b1 = mask_raw[1], b2 = mask_raw[2];
    int mode = (b1 != 0) ? 0 : ((b2 != 0) ? 2 : 1);
    int cnt = 0;
    if (mode == 0) {
        #pragma unroll
        for (int k = 0; k < 8; ++k) cnt += (mask_raw[(l * 8 + k) * B_SZ + b] != 0);
    } else if (mode == 1) {
        const int* mm = (const int*)mask_raw;
        #pragma unroll
        for (int k = 0; k < 8; ++k) cnt += (mm[(l * 8 + k) * B_SZ + b] != 0);
    } else {
        const float* mm = (const float*)mask_raw;
        #pragma unroll
        for (int k = 0; k < 8; ++k) cnt += (mm[(l * 8 + k) * B_SZ + b] != 0.0f);
    }
    #pragma unroll
    for (int off = 1; off < 64; off <<= 1) cnt += __shfl_xor(cnt, off);
    return cnt;
}

// ws layout (floats): [0..255] logZ_b ; [256..511] score_b

// Fully-fused CRF kernel: one block per batch, 3 waves.
//   wave0: forward recurrence  a_t = ee_t o (E^T a_{t-1}),  t = 1..m
//   wave1: backward recurrence y_{t-1} = E (ee_t o y_t),    t = len-1..m+1
//   wave2: Viterbi-path score (gathers), runs concurrently with the 256-step loops
// m = min(256, len-1). Recurrence bodies = R14 verbatim (proven 123 us, absmax 0).
// Each wave computes len itself (512 mask bytes, L2-resident) -- no extra barrier.
__global__ void __attribute__((amdgpu_flat_work_group_size(192, 192), amdgpu_waves_per_eu(1, 1)))
crf_fused_kernel(
        const float* __restrict__ emit,
        const unsigned char* __restrict__ mask_raw,
        const int* __restrict__ target,
        const float* __restrict__ trans,
        const float* __restrict__ strans,
        const float* __restrict__ etrans,
        float* __restrict__ logZ_out,
        float* __restrict__ score_out) {
    const int b   = blockIdx.x;
    const int tid = threadIdx.x;      // 0..191
    const int wid = tid >> 6;         // 0 = fwd, 1 = bwd, 2 = score
    const int l   = tid & 63;
    const int c0  = 2 * l, c1 = 2 * l + 1;

    __shared__ alignas(16) uint32 a32[64];   // fwd a-vector, bf16x2 packed
    __shared__ alignas(16) uint32 z32[64];   // bwd ee*y vector, bf16x2 packed
    __shared__ float meetA[N_ST], meetY[N_ST];
    __shared__ float maccSh[2], red2[2];

    const int len = wave_len(mask_raw, b, l);    // per-wave, uniform within wave
    const int m = (len - 1 < 256) ? (len - 1) : 256;
    const float* eb = emit + (size_t)b * N_ST;
    const size_t TS2 = (size_t)B_SZ * N_ST / 2;
    const f2v* ebv = (const f2v*)eb;

    if (wid == 0) {
        // ---- forward: E columns c0, c1 packed over i-pairs ----
        uint32 EA[64], EB[64];
        #pragma unroll
        for (int p = 0; p < 64; ++p) {
            EA[p] = pack2(__expf(trans[(2 * p) * N_ST + c0]), __expf(trans[(2 * p + 1) * N_ST + c0]));
            EB[p] = pack2(__expf(trans[(2 * p) * N_ST + c1]), __expf(trans[(2 * p + 1) * N_ST + c1]));
        }
        float aA = __expf(strans[c0] + eb[c0]);
        float aB = __expf(strans[c1] + eb[c1]);
        a32[l] = pack2(aA, aB);
        float Macc = 0.f, inv = 1.0f;
        #define EIDX(T) ((size_t)(((T) <= m) ? (T) : m) * TS2 + l)
        f2v p0 = ebv[EIDX(1)];
        f2v p1 = ebv[EIDX(2)];
        f2v p2 = ebv[EIDX(3)];
        f2v p3 = ebv[EIDX(4)];
        for (int t = 1; t <= m; ++t) {
            const f2v pn = ebv[EIDX(t + 4)];               // prefetch, 4 iters ahead
            const float ee0 = __expf(p0.x), ee1 = __expf(p0.y);
            float A0 = 0, A1 = 0, A2 = 0, A3 = 0, B0 = 0, B1 = 0, B2 = 0, B3 = 0;
            const uint4a* aw = (const uint4a*)a32;
            #pragma unroll
            for (int q = 0; q < 16; ++q) {
                const uint4 w = aw[q];                     // ds_read_b128 broadcast
                A0 = dot2b(w.x, EA[4 * q + 0], A0);  B0 = dot2b(w.x, EB[4 * q + 0], B0);
                A1 = dot2b(w.y, EA[4 * q + 1], A1);  B1 = dot2b(w.y, EB[4 * q + 1], B1);
                A2 = dot2b(w.z, EA[4 * q + 2], A2);  B2 = dot2b(w.z, EB[4 * q + 2], B2);
                A3 = dot2b(w.w, EA[4 * q + 3], A3);  B3 = dot2b(w.w, EB[4 * q + 3], B3);
            }
            const float rA = (A0 + A1) + (A2 + A3);
            const float rB = (B0 + B1) + (B2 + B3);
            Macc -= __logf(inv);                           // bookkeeping (off write path)
            aA = ee0 * rA * inv;                           // delayed uniform normalizer
            aB = ee1 * rB * inv;
            a32[l] = cvtpk(aA, aB);                        // ONE ds_write_b32
            inv = __builtin_amdgcn_rcpf(readlane0(rA));    // scalar path, NOT DS pipe
            p0 = p1; p1 = p2; p2 = p3; p3 = pn;
        }
        #undef EIDX
        meetA[c0] = aA; meetA[c1] = aB;
        if (l == 0) maccSh[0] = Macc;
    } else if (wid == 1) {
        // ---- backward: E rows c0, c1 packed over j-pairs ----
        uint32 RA[64], RB[64];
        #pragma unroll
        for (int p = 0; p < 64; ++p) {
            RA[p] = pack2(__expf(trans[c0 * N_ST + 2 * p]), __expf(trans[c0 * N_ST + 2 * p + 1]));
            RB[p] = pack2(__expf(trans[c1 * N_ST + 2 * p]), __expf(trans[c1 * N_ST + 2 * p + 1]));
        }
        float y0 = __expf(etrans[c0]);                     // y_{len-1} = exp(etrans)
        float y1 = __expf(etrans[c1]);
        float Maccb = 0.f, invb = 1.0f;
        const int t0 = len - 1;
        #define EIDXB(T) ((size_t)(((T) > m) ? (T) : (m + 1)) * TS2 + l)
        f2v p0 = ebv[EIDXB(t0)];
        f2v p1 = ebv[EIDXB(t0 - 1)];
        f2v p2 = ebv[EIDXB(t0 - 2)];
        f2v p3 = ebv[EIDXB(t0 - 3)];
        for (int t = t0; t > m; --t) {
            const f2v pn = ebv[EIDXB(t - 4)];              // prefetch, 4 iters ahead
            const float ee0 = __expf(p0.x), ee1 = __expf(p0.y);
            z32[l] = cvtpk(ee0 * y0, ee1 * y1);            // z = ee_t o y_t ; ONE write
            float R0 = 0, R1 = 0, R2 = 0, R3 = 0, S0 = 0, S1 = 0, S2 = 0, S3 = 0;
            const uint4a* zw = (const uint4a*)z32;
            #pragma unroll
            for (int q = 0; q < 16; ++q) {
                const uint4 w = zw[q];                     // ds_read_b128 broadcast
                R0 = dot2b(w.x, RA[4 * q + 0], R0);  S0 = dot2b(w.x, RB[4 * q + 0], S0);
                R1 = dot2b(w.y, RA[4 * q + 1], R1);  S1 = dot2b(w.y, RB[4 * q + 1], S1);
                R2 = dot2b(w.z, RA[4 * q + 2], R2);  S2 = dot2b(w.z, RB[4 * q + 2], S2);
                R3 = dot2b(w.w, RA[4 * q + 3], R3);  S3 = dot2b(w.w, RB[4 * q + 3], S3);
            }
            const float rR = (R0 + R1) + (R2 + R3);
            const float rS = (S0 + S1) + (S2 + S3);
            Maccb -= __logf(invb);
            y0 = rR * invb;                                // delayed normalizer, mirrored
            y1 = rS * invb;
            invb = __builtin_amdgcn_rcpf(readlane0(rR));
            p0 = p1; p1 = p2; p2 = p3; p3 = pn;
        }
        #undef EIDXB
        meetY[c0] = y0; meetY[c1] = y1;
        if (l == 0) maccSh[1] = Maccb;
    } else {
        // ---- score: Viterbi-path gathers, concurrent with the recurrences ----
        float local = 0.f;
        for (int t = l; t < len; t += 64) {
            int tgt = target[t * B_SZ + b];
            float v = emit[(size_t)t * (B_SZ * N_ST) + b * N_ST + tgt];
            if (t > 0) v += trans[target[(t - 1) * B_SZ + b] * N_ST + tgt];
            local += v;
        }
        if (l == 0) {
            local += strans[target[b]];
            local += etrans[target[(len - 1) * B_SZ + b]];
        }
        #pragma unroll
        for (int off = 1; off < 64; off <<= 1) local += __shfl_xor(local, off);
        if (l == 0) score_out[b] = local;
    }

    // ---- meet: logZ = MaccF + MaccB + log( sum_j a_m[j] * y_m[j] ) ----
    __syncthreads();
    if (wid < 2) {
        float v = meetA[tid] * meetY[tid];
        #pragma unroll
        for (int off = 1; off < 64; off <<= 1) v += __shfl_xor(v, off);
        if (l == 0) red2[wid] = v;
    }
    __syncthreads();
    if (tid == 0) logZ_out[b] = maccSh[0] + maccSh[1] + __logf(red2[0] + red2[1]);
}

__global__ __launch_bounds__(256) void finalize_kernel(
        const float* __restrict__ logZ,
        const float* __restrict__ score,
        float* __restrict__ out) {
    int tid = threadIdx.x;  // 256
    float v = logZ[tid] - score[tid];
    #pragma unroll
    for (int off = 1; off < 64; off <<= 1) v += __shfl_xor(v, off);
    __shared__ float p[4];
    if ((tid & 63) == 0) p[tid >> 6] = v;
    __syncthreads();
    if (tid == 0) out[0] = (p[0] + p[1] + p[2] + p[3]) / 256.0f;
}

extern "C" void kernel_launch(void* const* d_in, const int* in_sizes, int n_in,
                              void* d_out, int out_size, void* d_ws, size_t ws_size,
                              hipStream_t stream) {
    const float*         emit   = (const float*)d_in[0];
    const int*           target = (const int*)d_in[1];
    const unsigned char* mask   = (const unsigned char*)d_in[2];
    const float*         trans  = (const float*)d_in[3];
    const float*         strans = (const float*)d_in[4];
    const float*         etrans = (const float*)d_in[5];

    float* ws     = (float*)d_ws;
    float* logZb  = ws;            // 256
    float* scoreb = ws + 256;      // 256

    crf_fused_kernel<<<B_SZ, 192, 0, stream>>>(emit, mask, target, trans, strans, etrans,
                                               logZb, scoreb);
    finalize_kernel<<<1, 256, 0, stream>>>(logZb, scoreb, (float*)d_out);
}